// Round 15
// baseline (720.059 us; speedup 1.0000x reference)
//
#include <hip/hip_runtime.h>
#include <hip/hip_bf16.h>

// DeepSeekMoE: B=4,S=2048,D=1024,H=1024,E=7,NS=1,topk=3. N=8192 tokens.
#define N_TOK 8192
#define DIM   1024
#define NE    7
#define MT_TILES 136   // <= 103 routed + 32 shared + slack; grids 136*8 = 1088

typedef __attribute__((ext_vector_type(8))) short bf16x8;
typedef __attribute__((ext_vector_type(4))) float f32x4;

typedef __attribute__((address_space(3))) ushort lds_us_t;
typedef __attribute__((address_space(1))) const ushort glb_us_t;

__device__ __forceinline__ void gll16(const ushort* g, ushort* l) {
    __builtin_amdgcn_global_load_lds((glb_us_t*)g, (lds_us_t*)l, 16, 0, 0);
}

__device__ __forceinline__ unsigned short f2bf(float f) {
    unsigned int u = __builtin_bit_cast(unsigned int, f);
    u += 0x7fffu + ((u >> 16) & 1u);   // RNE
    return (unsigned short)(u >> 16);
}

__device__ __forceinline__ float bf2f(unsigned short b) {
    unsigned int u = ((unsigned int)b) << 16;
    return __builtin_bit_cast(float, u);
}

__device__ __forceinline__ float siluf(float v) { return v / (1.f + __expf(-v)); }

// ---------------- prep: weight transpose+convert  ||  gate (fused) -----------
__global__ void __launch_bounds__(256)
prep_kernel(const float* __restrict__ w1, const float* __restrict__ wg,
            const float* __restrict__ w2, const float* __restrict__ sw1,
            const float* __restrict__ sw2,
            ushort* __restrict__ w1T, ushort* __restrict__ wgT,
            ushort* __restrict__ w2T,
            const float* __restrict__ x, const float* __restrict__ gw,
            const float* __restrict__ gb, const float* __restrict__ bia,
            int* __restrict__ topk_e, float* __restrict__ topk_w,
            int* __restrict__ counts, ushort* __restrict__ xb)
{
    __shared__ float smem[NE * DIM + 8];   // 28.7 KB, aliased by both branches
    const int tid = threadIdx.x;
    const int z = blockIdx.z;

    if (z < 23) {
        const float* src; ushort* dst;
        if (z < 7)       { src = w1 + (size_t)z * (DIM*DIM);        dst = w1T + (size_t)z * (DIM*DIM); }
        else if (z < 14) { src = wg + (size_t)(z - 7) * (DIM*DIM);  dst = wgT + (size_t)(z - 7) * (DIM*DIM); }
        else if (z < 21) { src = w2 + (size_t)(z - 14) * (DIM*DIM); dst = w2T + (size_t)(z - 14) * (DIM*DIM); }
        else if (z == 21){ src = sw1; dst = w1T + (size_t)NE * (DIM*DIM); }
        else             { src = sw2; dst = w2T + (size_t)NE * (DIM*DIM); }
        float (*t)[33] = (float(*)[33])smem;
        int bx = blockIdx.x * 32, by = blockIdx.y * 32;
        int lx = tid & 31, ly = tid >> 5;
#pragma unroll
        for (int i = 0; i < 32; i += 8)
            t[ly + i][lx] = src[(size_t)(by + ly + i) * DIM + bx + lx];
        __syncthreads();
#pragma unroll
        for (int i = 0; i < 32; i += 8) {
            int r = ly + i;
            dst[(size_t)(bx + r) * DIM + by + lx] = f2bf(t[lx][r]);
        }
        return;
    }

    float (*gwT)[DIM] = (float(*)[DIM])smem;
    int* cnt = (int*)(smem + NE * DIM);
    const int gblk = blockIdx.y * 32 + blockIdx.x;    // 0..1023
    if (tid < NE) cnt[tid] = 0;
    for (int t = tid; t < NE * DIM; t += 256) {
        int d = t / NE, e = t - d * NE;
        gwT[e][d] = gw[t];
    }
    __syncthreads();

    const int lane = tid & 63, wid = tid >> 6;
#pragma unroll
    for (int tt = 0; tt < 2; tt++) {
        const int n = gblk * 8 + wid * 2 + tt;
        const float4* xr = (const float4*)(x + (size_t)n * DIM);
        ushort4* xo = (ushort4*)(xb + (size_t)n * DIM);
        float p[NE];
#pragma unroll
        for (int e = 0; e < NE; e++) p[e] = 0.f;
#pragma unroll
        for (int it = 0; it < 4; it++) {
            int i4 = it * 64 + lane;
            float4 v = xr[i4];
            ushort4 o;
            o.x = f2bf(v.x); o.y = f2bf(v.y); o.z = f2bf(v.z); o.w = f2bf(v.w);
            xo[i4] = o;
            int d = i4 * 4;
#pragma unroll
            for (int e = 0; e < NE; e++) {
                float4 g = *(const float4*)&gwT[e][d];
                p[e] += v.x * g.x + v.y * g.y + v.z * g.z + v.w * g.w;
            }
        }
#pragma unroll
        for (int e = 0; e < NE; e++)
            for (int off = 32; off; off >>= 1) p[e] += __shfl_xor(p[e], off);
        if (lane == 0) {
            float l[NE], m = -1e30f;
#pragma unroll
            for (int e = 0; e < NE; e++) { l[e] = p[e] + gb[e]; m = fmaxf(m, l[e]); }
            float s = 0.f;
#pragma unroll
            for (int e = 0; e < NE; e++) { l[e] = __expf(l[e] - m); s += l[e]; }
            float inv = 1.f / s;
#pragma unroll
            for (int e = 0; e < NE; e++) l[e] *= inv;          // probs
            float adj[NE]; bool used[NE];
#pragma unroll
            for (int e = 0; e < NE; e++) { adj[e] = l[e] + bia[e]; used[e] = false; }
            int sel[3]; float w[3]; float ws = 0.f;
            for (int k = 0; k < 3; k++) {
                int b = -1; float bv = -1e30f;
                for (int e = 0; e < NE; e++)
                    if (!used[e] && adj[e] > bv) { bv = adj[e]; b = e; }
                used[b] = true; sel[k] = b; w[k] = l[b]; ws += w[k];
            }
            float iws = 1.f / ws;
            for (int k = 0; k < 3; k++) {
                topk_e[n * 3 + k] = sel[k];
                topk_w[n * 3 + k] = w[k] * iws;
                atomicAdd(&cnt[sel[k]], 1);
            }
        }
    }
    __syncthreads();
    if (tid < NE) atomicAdd(&counts[tid], cnt[tid]);
}

// --------- setup: thread-0 scan (7 experts) + parallel tile-list fill --------
__global__ void __launch_bounds__(64)
setup_kernel(int* __restrict__ ctrl)
{
    __shared__ int eoff[NE + 1];
    __shared__ int tb[NE + 1];
    const int tid = threadIdx.x;
    if (tid == 0) {
        int off = 0, t = 0;
        for (int e = 0; e < NE; e++) {
            eoff[e] = off;
            tb[e] = t;
            ctrl[16 + e] = off;                       // cursor
            int padc = (ctrl[8 + e] + 255) & ~255;
            off += padc;
            t += padc >> 8;
        }
        eoff[NE] = off;  tb[NE] = t;
        ctrl[2] = off;                                // shared_base
        ctrl[1] = off + N_TOK;                        // total rows
        ctrl[0] = t + (N_TOK >> 8);                   // tile count
    }
    __syncthreads();
    if (tid <= NE) {
        int* tiles = ctrl + 32;
        int o = eoff[tid];
        int t0 = tb[tid];
        int nt = (tid == NE) ? (N_TOK >> 8) : (tb[tid + 1] - tb[tid]);
        for (int i = 0; i < nt; i++) {
            tiles[(t0 + i) * 2]     = tid;            // expert id (NE = shared)
            tiles[(t0 + i) * 2 + 1] = o + i * 256;
        }
    }
}

// --------- scatter: block-aggregated slot reservation (+ ident fill) ---------
__global__ void __launch_bounds__(256)
scatter_kernel(const int* __restrict__ topk_e, int* __restrict__ ctrl,
               int* __restrict__ row_tok, int* __restrict__ slots)
{
    __shared__ int lcnt[NE];
    __shared__ int base[NE];
    const int tid = threadIdx.x;
    const int n = blockIdx.x * 256 + tid;
    if (tid < NE) lcnt[tid] = 0;
    __syncthreads();
    row_tok[ctrl[2] + n] = n;                         // identity fill (shared)
    int e[3], ofs[3];
#pragma unroll
    for (int k = 0; k < 3; k++) {
        e[k] = topk_e[n * 3 + k];
        ofs[k] = atomicAdd(&lcnt[e[k]], 1);           // LDS atomic
    }
    __syncthreads();
    if (tid < NE) base[tid] = atomicAdd(&ctrl[16 + tid], lcnt[tid]);
    __syncthreads();
#pragma unroll
    for (int k = 0; k < 3; k++) {
        int slot = base[e[k]] + ofs[k];
        row_tok[slot] = n;
        slots[n * 3 + k] = slot;
    }
}

// ============ GEMM: A via LDS (2-barrier dbuf), B direct global->VGPR ========
// LDS-port offload: B fragments stream through L1/L2 (per-lane contiguous 16B,
// 16 lines/frag, L1-resident slice), halving LDS port pressure. B regs
// ping-pong: load tile t+1's frags before compute(t); vmcnt(0) drains both.

// ---- G1: 256x128 dual-B ------------------------------------------------------
__global__ void __launch_bounds__(512, 2)
g1_kernel(const ushort* __restrict__ Xb, const ushort* __restrict__ W1,
          const ushort* __restrict__ WG, const float* __restrict__ sb1,
          ushort* __restrict__ H, const int* __restrict__ row_tok,
          const int* __restrict__ ctrl)
{
    __shared__ ushort lds[16384];   // 32 KB: 2 bufs x 8192 (A only)
    int bx, col0;
    {
        int L = blockIdx.x + blockIdx.y * MT_TILES;          // grid 136x8 = 1088
        int D = (L & 7) * MT_TILES + (L >> 3);
        bx = D >> 3;  col0 = (D & 7) * 128;
    }
    if (bx >= ctrl[0]) return;
    const int e     = ctrl[32 + 2*bx];
    const int slot0 = ctrl[32 + 2*bx + 1];
    const bool gated = (e != NE);
    const int tt = threadIdx.x;
    const int lane = tt & 63, wid = tt >> 6;
    const int wm = wid >> 1, wn = wid & 1;
    const int wofs = wid * 512;
    const int hi = lane >> 4, lr = lane & 15;

    // A staging source (inverse-swizzled global address)
    const int slog = (tt & 7) ^ ((tt >> 3) & 7);
    const int kk0 = (slog & 3) * 8;
    const int r0 = ((tt >> 3) << 1) + (slog >> 2);
    const ushort* pA0 = Xb + (size_t)row_tok[slot0 + r0] * DIM + kk0;
    const ushort* pA1 = Xb + (size_t)row_tok[slot0 + r0 + 128] * DIM + kk0;

    // B direct-fragment bases: frag n, tile kt at  + n*16*DIM + kt*32
    const ushort* B1e = W1 + (size_t)e * (DIM*DIM);
    const ushort* B2e = gated ? (WG + (size_t)e * (DIM*DIM))
                              : (W1 + (size_t)NE * (DIM*DIM));
    const ushort* pBg1 = B1e + (size_t)(col0 + wn*64 + lr) * DIM + hi*8;
    const ushort* pBg2 = B2e + (size_t)(col0 + wn*64 + lr) * DIM + hi*8;

    // A fragment read offsets (swizzled)
    int aoff[4];
#pragma unroll
    for (int m = 0; m < 4; m++) {
        int row = wm*64 + m*16 + lr;
        int lrow = row >> 1;
        int sl = ((row & 1) << 2) | hi;
        aoff[m] = lrow*64 + (sl ^ (lrow & 7))*8;
    }

    f32x4 zero4 = {0.f, 0.f, 0.f, 0.f};
    f32x4 acc1[4][4], acc2[4][4];
#pragma unroll
    for (int m = 0; m < 4; m++)
#pragma unroll
        for (int n = 0; n < 4; n++) { acc1[m][n] = zero4; acc2[m][n] = zero4; }

    bf16x8 bc1[4], bc2[4], bn1[4], bn2[4];

    auto stageA = [&](int buf, int kte) {
        ushort* b = &lds[buf * 8192];
        gll16(pA0 + kte, b + wofs);
        gll16(pA1 + kte, b + 4096 + wofs);
    };
    auto loadB = [&](bf16x8* d1, bf16x8* d2, int kt) {
#pragma unroll
        for (int n = 0; n < 4; n++) {
            d1[n] = *(const bf16x8*)(pBg1 + (size_t)n * 16 * DIM + kt * 32);
            if (gated) d2[n] = *(const bf16x8*)(pBg2 + (size_t)n * 16 * DIM + kt * 32);
        }
    };
    auto compute = [&](int buf, const bf16x8* b1, const bf16x8* b2) {
        const ushort* Ab = &lds[buf * 8192];
        bf16x8 a[4];
#pragma unroll
        for (int m = 0; m < 4; m++) a[m] = *(const bf16x8*)(Ab + aoff[m]);
        __builtin_amdgcn_s_setprio(1);
#pragma unroll
        for (int m = 0; m < 4; m++)
#pragma unroll
            for (int n = 0; n < 4; n++)
                acc1[m][n] = __builtin_amdgcn_mfma_f32_16x16x32_bf16(a[m], b1[n], acc1[m][n], 0, 0, 0);
        __builtin_amdgcn_s_setprio(0);
        if (gated) {
            __builtin_amdgcn_s_setprio(1);
#pragma unroll
            for (int m = 0; m < 4; m++)
#pragma unroll
                for (int n = 0; n < 4; n++)
                    acc2[m][n] = __builtin_amdgcn_mfma_f32_16x16x32_bf16(a[m], b2[n], acc2[m][n], 0, 0, 0);
            __builtin_amdgcn_s_setprio(0);
        }
    };

    stageA(0, 0); loadB(bc1, bc2, 0);
    asm volatile("s_waitcnt vmcnt(0)" ::: "memory");
    __builtin_amdgcn_s_barrier();
    asm volatile("" ::: "memory");
    for (int tp = 0; tp < 15; ++tp) {        // tiles 0..29 in ping-pong pairs
        int t = tp * 2;
        stageA(1, (t + 1) * 32); loadB(bn1, bn2, t + 1);
        compute(0, bc1, bc2);
        asm volatile("s_waitcnt vmcnt(0)" ::: "memory");
        __builtin_amdgcn_s_barrier();
        asm volatile("" ::: "memory");
        stageA(0, (t + 2) * 32); loadB(bc1, bc2, t + 2);
        compute(1, bn1, bn2);
        asm volatile("s_waitcnt vmcnt(0)" ::: "memory");
        __builtin_amdgcn_s_barrier();
        asm volatile("" ::: "memory");
    }
    stageA(1, 31 * 32); loadB(bn1, bn2, 31);
    compute(0, bc1, bc2);                    // tile 30
    asm volatile("s_waitcnt vmcnt(0)" ::: "memory");
    __builtin_amdgcn_s_barrier();
    asm volatile("" ::: "memory");
    compute(1, bn1, bn2);                    // tile 31

    // epilogue: SwiGLU (routed) / bias-silu (shared)
#pragma unroll
    for (int m = 0; m < 4; m++)
#pragma unroll
        for (int n = 0; n < 4; n++)
#pragma unroll
            for (int r = 0; r < 4; r++) {
                int row = slot0 + wm*64 + m*16 + hi*4 + r;
                int col = col0 + wn*64 + n*16 + lr;
                float v1 = acc1[m][n][r];
                float h = gated ? siluf(v1) * acc2[m][n][r]
                                : siluf(v1 + sb1[col]);
                H[(size_t)row * DIM + col] = f2bf(h);
            }
}

// ---- G2: 256x128 single-B ----------------------------------------------------
__global__ void __launch_bounds__(512, 2)
g2_kernel(const ushort* __restrict__ H, const ushort* __restrict__ W2,
          const float* __restrict__ sb2, float* __restrict__ out,
          ushort* __restrict__ y2, const int* __restrict__ ctrl)
{
    __shared__ ushort lds[16384];   // 32 KB: 2 bufs x 8192 (A only)
    int bx, col0;
    {
        int L = blockIdx.x + blockIdx.y * MT_TILES;          // grid 136x8 = 1088
        int D = (L & 7) * MT_TILES + (L >> 3);
        bx = D >> 3;  col0 = (D & 7) * 128;
    }
    if (bx >= ctrl[0]) return;
    const int e     = ctrl[32 + 2*bx];
    const int slot0 = ctrl[32 + 2*bx + 1];
    const int sbase = ctrl[2];
    const int tt = threadIdx.x;
    const int lane = tt & 63, wid = tt >> 6;
    const int wm = wid >> 1, wn = wid & 1;
    const int wofs = wid * 512;
    const int hi = lane >> 4, lr = lane & 15;

    const int slog = (tt & 7) ^ ((tt >> 3) & 7);
    const int kk0 = (slog & 3) * 8;
    const int r0 = ((tt >> 3) << 1) + (slog >> 2);
    const ushort* pA0 = H + (size_t)(slot0 + r0) * DIM + kk0;
    const ushort* pA1 = H + (size_t)(slot0 + r0 + 128) * DIM + kk0;
    const ushort* Be  = W2 + (size_t)e * (DIM*DIM);
    const ushort* pBg = Be + (size_t)(col0 + wn*64 + lr) * DIM + hi*8;

    int aoff[4];
#pragma unroll
    for (int m = 0; m < 4; m++) {
        int row = wm*64 + m*16 + lr;
        int lrow = row >> 1;
        int sl = ((row & 1) << 2) | hi;
        aoff[m] = lrow*64 + (sl ^ (lrow & 7))*8;
    }

    f32x4 zero4 = {0.f, 0.f, 0.f, 0.f};
    f32x4 acc[4][4];
#pragma unroll
    for (int m = 0; m < 4; m++)
#pragma unroll
        for (int n = 0; n < 4; n++) acc[m][n] = zero4;

    bf16x8 bc[4], bn[4];

    auto stageA = [&](int buf, int kte) {
        ushort* b = &lds[buf * 8192];
        gll16(pA0 + kte, b + wofs);
        gll16(pA1 + kte, b + 4096 + wofs);
    };
    auto loadB = [&](bf16x8* d, int kt) {
#pragma unroll
        for (int n = 0; n < 4; n++)
            d[n] = *(const bf16x8*)(pBg + (size_t)n * 16 * DIM + kt * 32);
    };
    auto compute = [&](int buf, const bf16x8* b) {
        const ushort* Ab = &lds[buf * 8192];
        bf16x8 a[4];
#pragma unroll
        for (int m = 0; m < 4; m++) a[m] = *(const bf16x8*)(Ab + aoff[m]);
        __builtin_amdgcn_s_setprio(1);
#pragma unroll
        for (int m = 0; m < 4; m++)
#pragma unroll
            for (int n = 0; n < 4; n++)
                acc[m][n] = __builtin_amdgcn_mfma_f32_16x16x32_bf16(a[m], b[n], acc[m][n], 0, 0, 0);
        __builtin_amdgcn_s_setprio(0);
    };

    stageA(0, 0); loadB(bc, 0);
    asm volatile("s_waitcnt vmcnt(0)" ::: "memory");
    __builtin_amdgcn_s_barrier();
    asm volatile("" ::: "memory");
    for (int tp = 0; tp < 15; ++tp) {
        int t = tp * 2;
        stageA(1, (t + 1) * 32); loadB(bn, t + 1);
        compute(0, bc);
        asm volatile("s_waitcnt vmcnt(0)" ::: "memory");
        __builtin_amdgcn_s_barrier();
        asm volatile("" ::: "memory");
        stageA(0, (t + 2) * 32); loadB(bc, t + 2);
        compute(1, bn);
        asm volatile("s_waitcnt vmcnt(0)" ::: "memory");
        __builtin_amdgcn_s_barrier();
        asm volatile("" ::: "memory");
    }
    stageA(1, 31 * 32); loadB(bn, 31);
    compute(0, bc);                          // tile 30
    asm volatile("s_waitcnt vmcnt(0)" ::: "memory");
    __builtin_amdgcn_s_barrier();
    asm volatile("" ::: "memory");
    compute(1, bn);                          // tile 31

#pragma unroll
    for (int m = 0; m < 4; m++)
#pragma unroll
        for (int n = 0; n < 4; n++)
#pragma unroll
            for (int r = 0; r < 4; r++) {
                int row = slot0 + wm*64 + m*16 + hi*4 + r;
                int col = col0 + wn*64 + n*16 + lr;
                float v = acc[m][n][r];
                if (e != NE) y2[(size_t)row * DIM + col] = f2bf(v);
                else         out[(size_t)(row - sbase) * DIM + col] = v + sb2[col];
            }
}

// --------- combine: out[n] += sum_k w_k * y2[slot_k(n)] ----------------------
__global__ void __launch_bounds__(256)
combine_kernel(const ushort* __restrict__ y2, const int* __restrict__ slots,
               const float* __restrict__ topk_w, float* __restrict__ out)
{
    __shared__ int ss[3];
    __shared__ float sw[3];
    const int n = blockIdx.x, tid = threadIdx.x;
    if (tid < 3) { ss[tid] = slots[n * 3 + tid]; sw[tid] = topk_w[n * 3 + tid]; }
    __syncthreads();
    float4* o4 = (float4*)(out + (size_t)n * DIM);
    float4 o = o4[tid];
#pragma unroll
    for (int k = 0; k < 3; k++) {
        const ushort4 yv = *(const ushort4*)(y2 + (size_t)ss[k] * DIM + tid * 4);
        float w = sw[k];
        o.x += w * bf2f(yv.x);
        o.y += w * bf2f(yv.y);
        o.z += w * bf2f(yv.z);
        o.w += w * bf2f(yv.w);
    }
    o4[tid] = o;
}

extern "C" void kernel_launch(void* const* d_in, const int* in_sizes, int n_in,
                              void* d_out, int out_size, void* d_ws, size_t ws_size,
                              hipStream_t stream)
{
    const float* x    = (const float*)d_in[0];
    const float* gw   = (const float*)d_in[1];
    const float* gb   = (const float*)d_in[2];
    const float* bia  = (const float*)d_in[3];
    const float* w1   = (const float*)d_in[4];
    const float* wg   = (const float*)d_in[5];
    const float* w2   = (const float*)d_in[6];
    const float* sw1  = (const float*)d_in[7];
    const float* sb1  = (const float*)d_in[8];
    const float* sw2  = (const float*)d_in[9];
    const float* sb2  = (const float*)d_in[10];
    float* out = (float*)d_out;

    // Workspace layout (bytes); total 173,452,288 <= proven ws_size >= 186,625,024.
    char* ws = (char*)d_ws;
    int*    ctrl   = (int*)   (ws + 0);          // [0]=ntiles [1]=rows [2]=shared_base, +8 counts, +16 cursors, +32 tiles
    int*    topk_e = (int*)   (ws + 4096);       //  98,304
    float*  topk_w = (float*) (ws + 102400);     //  98,304
    int*    slots  = (int*)   (ws + 200704);     //  98,304
    int*    row_tok= (int*)   (ws + 299008);     // 138,240 (34560 ints) -> pad to 437,248
    ushort* w1T    = (ushort*)(ws + 437248);     // 8 x 2MB (e7 = sw1T)
    ushort* wgT    = (ushort*)(ws + 17214464);   // 7 x 2MB
    ushort* w2T    = (ushort*)(ws + 31894528);   // 8 x 2MB (e7 = sw2T)
    ushort* h1     = (ushort*)(ws + 48671744);   // 34560 x 1024 bf16 = 70,778,880
    ushort* y2     = (ushort*)(ws + 119450624);  // 26368 x 1024 bf16 = 54,001,664 -> end 173,452,288
    ushort* xb     = y2;                         // alias: xb dead before g2 writes y2

    hipMemsetAsync(ctrl, 0, 4096, stream);
    hipMemsetAsync(row_tok, 0, 34560 * 4, stream);   // pad slots default to token 0
    prep_kernel<<<dim3(32, 32, 24), 256, 0, stream>>>(w1, wg, w2, sw1, sw2,
                                                      w1T, wgT, w2T,
                                                      x, gw, gb, bia,
                                                      topk_e, topk_w, ctrl + 8, xb);
    setup_kernel<<<1, 64, 0, stream>>>(ctrl);
    scatter_kernel<<<N_TOK / 256, 256, 0, stream>>>(topk_e, ctrl, row_tok, slots);

    g1_kernel<<<dim3(MT_TILES, 8), 512, 0, stream>>>(xb, w1T, wgT, sb1, h1,
                                                     row_tok, ctrl);
    g2_kernel<<<dim3(MT_TILES, 8), 512, 0, stream>>>(h1, w2T, sb2, out, y2, ctrl);
    combine_kernel<<<N_TOK, 256, 0, stream>>>(y2, slots, topk_w, out);
}

// Round 16
// 360.036 us; speedup vs baseline: 2.0000x; 2.0000x over previous
//
#include <hip/hip_runtime.h>
#include <hip/hip_bf16.h>

// DeepSeekMoE: B=4,S=2048,D=1024,H=1024,E=7,NS=1,topk=3. N=8192 tokens.
#define N_TOK 8192
#define DIM   1024
#define NE    7
#define MT_TILES 136   // <= 103 routed + 32 shared + slack; grids 136*8 = 1088

typedef __attribute__((ext_vector_type(8))) short bf16x8;
typedef __attribute__((ext_vector_type(4))) float f32x4;

typedef __attribute__((address_space(3))) ushort lds_us_t;
typedef __attribute__((address_space(1))) const ushort glb_us_t;

__device__ __forceinline__ void gll16(const ushort* g, ushort* l) {
    __builtin_amdgcn_global_load_lds((glb_us_t*)g, (lds_us_t*)l, 16, 0, 0);
}

__device__ __forceinline__ unsigned short f2bf(float f) {
    unsigned int u = __builtin_bit_cast(unsigned int, f);
    u += 0x7fffu + ((u >> 16) & 1u);   // RNE
    return (unsigned short)(u >> 16);
}

__device__ __forceinline__ float bf2f(unsigned short b) {
    unsigned int u = ((unsigned int)b) << 16;
    return __builtin_bit_cast(float, u);
}

__device__ __forceinline__ float siluf(float v) { return v / (1.f + __expf(-v)); }

// ---------------- prep: weight transpose+convert  ||  gate (fused) -----------
// Grid (32,32,24): z<23 -> one 32x32 transpose slice; z==23 -> gate sub-block
// (1024 sub-blocks x 8 tokens). Independent work in ONE dispatch.
__global__ void __launch_bounds__(256)
prep_kernel(const float* __restrict__ w1, const float* __restrict__ wg,
            const float* __restrict__ w2, const float* __restrict__ sw1,
            const float* __restrict__ sw2,
            ushort* __restrict__ w1T, ushort* __restrict__ wgT,
            ushort* __restrict__ w2T,
            const float* __restrict__ x, const float* __restrict__ gw,
            const float* __restrict__ gb, const float* __restrict__ bia,
            int* __restrict__ topk_e, float* __restrict__ topk_w,
            int* __restrict__ counts, ushort* __restrict__ xb)
{
    __shared__ float smem[NE * DIM + 8];   // 28.7 KB, aliased by both branches
    const int tid = threadIdx.x;
    const int z = blockIdx.z;

    if (z < 23) {
        const float* src; ushort* dst;
        if (z < 7)       { src = w1 + (size_t)z * (DIM*DIM);        dst = w1T + (size_t)z * (DIM*DIM); }
        else if (z < 14) { src = wg + (size_t)(z - 7) * (DIM*DIM);  dst = wgT + (size_t)(z - 7) * (DIM*DIM); }
        else if (z < 21) { src = w2 + (size_t)(z - 14) * (DIM*DIM); dst = w2T + (size_t)(z - 14) * (DIM*DIM); }
        else if (z == 21){ src = sw1; dst = w1T + (size_t)NE * (DIM*DIM); }
        else             { src = sw2; dst = w2T + (size_t)NE * (DIM*DIM); }
        float (*t)[33] = (float(*)[33])smem;
        int bx = blockIdx.x * 32, by = blockIdx.y * 32;
        int lx = tid & 31, ly = tid >> 5;
#pragma unroll
        for (int i = 0; i < 32; i += 8)
            t[ly + i][lx] = src[(size_t)(by + ly + i) * DIM + bx + lx];
        __syncthreads();
#pragma unroll
        for (int i = 0; i < 32; i += 8) {
            int r = ly + i;
            dst[(size_t)(bx + r) * DIM + by + lx] = f2bf(t[lx][r]);
        }
        return;
    }

    float (*gwT)[DIM] = (float(*)[DIM])smem;
    int* cnt = (int*)(smem + NE * DIM);
    const int gblk = blockIdx.y * 32 + blockIdx.x;    // 0..1023
    if (tid < NE) cnt[tid] = 0;
    for (int t = tid; t < NE * DIM; t += 256) {
        int d = t / NE, e = t - d * NE;
        gwT[e][d] = gw[t];
    }
    __syncthreads();

    const int lane = tid & 63, wid = tid >> 6;
#pragma unroll
    for (int tt = 0; tt < 2; tt++) {
        const int n = gblk * 8 + wid * 2 + tt;
        const float4* xr = (const float4*)(x + (size_t)n * DIM);
        ushort4* xo = (ushort4*)(xb + (size_t)n * DIM);
        float p[NE];
#pragma unroll
        for (int e = 0; e < NE; e++) p[e] = 0.f;
#pragma unroll
        for (int it = 0; it < 4; it++) {
            int i4 = it * 64 + lane;
            float4 v = xr[i4];
            ushort4 o;
            o.x = f2bf(v.x); o.y = f2bf(v.y); o.z = f2bf(v.z); o.w = f2bf(v.w);
            xo[i4] = o;
            int d = i4 * 4;
#pragma unroll
            for (int e = 0; e < NE; e++) {
                float4 g = *(const float4*)&gwT[e][d];
                p[e] += v.x * g.x + v.y * g.y + v.z * g.z + v.w * g.w;
            }
        }
#pragma unroll
        for (int e = 0; e < NE; e++)
            for (int off = 32; off; off >>= 1) p[e] += __shfl_xor(p[e], off);
        if (lane == 0) {
            float l[NE], m = -1e30f;
#pragma unroll
            for (int e = 0; e < NE; e++) { l[e] = p[e] + gb[e]; m = fmaxf(m, l[e]); }
            float s = 0.f;
#pragma unroll
            for (int e = 0; e < NE; e++) { l[e] = __expf(l[e] - m); s += l[e]; }
            float inv = 1.f / s;
#pragma unroll
            for (int e = 0; e < NE; e++) l[e] *= inv;          // probs
            float adj[NE]; bool used[NE];
#pragma unroll
            for (int e = 0; e < NE; e++) { adj[e] = l[e] + bia[e]; used[e] = false; }
            int sel[3]; float w[3]; float ws = 0.f;
            for (int k = 0; k < 3; k++) {
                int b = -1; float bv = -1e30f;
                for (int e = 0; e < NE; e++)
                    if (!used[e] && adj[e] > bv) { bv = adj[e]; b = e; }
                used[b] = true; sel[k] = b; w[k] = l[b]; ws += w[k];
            }
            float iws = 1.f / ws;
            for (int k = 0; k < 3; k++) {
                topk_e[n * 3 + k] = sel[k];
                topk_w[n * 3 + k] = w[k] * iws;
                atomicAdd(&cnt[sel[k]], 1);
            }
        }
    }
    __syncthreads();
    if (tid < NE) atomicAdd(&counts[tid], cnt[tid]);
}

// --------- setup: thread-0 scan (7 experts) + parallel tile-list fill --------
__global__ void __launch_bounds__(64)
setup_kernel(int* __restrict__ ctrl)
{
    __shared__ int eoff[NE + 1];
    __shared__ int tb[NE + 1];
    const int tid = threadIdx.x;
    if (tid == 0) {
        int off = 0, t = 0;
        for (int e = 0; e < NE; e++) {
            eoff[e] = off;
            tb[e] = t;
            ctrl[16 + e] = off;                       // cursor
            int padc = (ctrl[8 + e] + 255) & ~255;
            off += padc;
            t += padc >> 8;
        }
        eoff[NE] = off;  tb[NE] = t;
        ctrl[2] = off;                                // shared_base
        ctrl[1] = off + N_TOK;                        // total rows
        ctrl[0] = t + (N_TOK >> 8);                   // tile count
    }
    __syncthreads();
    if (tid <= NE) {
        int* tiles = ctrl + 32;
        int o = eoff[tid];
        int t0 = tb[tid];
        int nt = (tid == NE) ? (N_TOK >> 8) : (tb[tid + 1] - tb[tid]);
        for (int i = 0; i < nt; i++) {
            tiles[(t0 + i) * 2]     = tid;            // expert id (NE = shared)
            tiles[(t0 + i) * 2 + 1] = o + i * 256;
        }
    }
}

// --------- scatter: block-aggregated slot reservation (+ ident fill) ---------
__global__ void __launch_bounds__(256)
scatter_kernel(const int* __restrict__ topk_e, int* __restrict__ ctrl,
               int* __restrict__ row_tok, int* __restrict__ slots)
{
    __shared__ int lcnt[NE];
    __shared__ int base[NE];
    const int tid = threadIdx.x;
    const int n = blockIdx.x * 256 + tid;
    if (tid < NE) lcnt[tid] = 0;
    __syncthreads();
    row_tok[ctrl[2] + n] = n;                         // identity fill (shared)
    int e[3], ofs[3];
#pragma unroll
    for (int k = 0; k < 3; k++) {
        e[k] = topk_e[n * 3 + k];
        ofs[k] = atomicAdd(&lcnt[e[k]], 1);           // LDS atomic
    }
    __syncthreads();
    if (tid < NE) base[tid] = atomicAdd(&ctrl[16 + tid], lcnt[tid]);
    __syncthreads();
#pragma unroll
    for (int k = 0; k < 3; k++) {
        int slot = base[e[k]] + ofs[k];
        row_tok[slot] = n;
        slots[n * 3 + k] = slot;
    }
}

// ============ GEMM: 2-barrier double-buffer (proven fastest schedule) ========
// Dual-row packed LDS swizzle (2 lanes/bank, free); gll16 linear dest with
// inverse-swizzled global source (rule #21). 2 blocks/CU hide the drain.

// ---- G1: 256x128 dual-B, 64 KB dbuf -----------------------------------------
__global__ void __launch_bounds__(512, 2)
g1_kernel(const ushort* __restrict__ Xb, const ushort* __restrict__ W1,
          const ushort* __restrict__ WG, const float* __restrict__ sb1,
          ushort* __restrict__ H, const int* __restrict__ row_tok,
          const int* __restrict__ ctrl)
{
    __shared__ ushort lds[32768];   // 64 KB: 2 bufs x (8192 A + 4096 B1 + 4096 B2)
    int bx, col0;
    {
        int L = blockIdx.x + blockIdx.y * MT_TILES;          // grid 136x8 = 1088
        int D = (L & 7) * MT_TILES + (L >> 3);
        bx = D >> 3;  col0 = (D & 7) * 128;
    }
    if (bx >= ctrl[0]) return;
    const int e     = ctrl[32 + 2*bx];
    const int slot0 = ctrl[32 + 2*bx + 1];
    const bool gated = (e != NE);
    const int tt = threadIdx.x;
    const int lane = tt & 63, wid = tt >> 6;
    const int wm = wid >> 1, wn = wid & 1;
    const int wofs = wid * 512;

    const int slog = (tt & 7) ^ ((tt >> 3) & 7);
    const int kk0 = (slog & 3) * 8;
    const int r0 = ((tt >> 3) << 1) + (slog >> 2);
    const ushort* pA0 = Xb + (size_t)row_tok[slot0 + r0] * DIM + kk0;
    const ushort* pA1 = Xb + (size_t)row_tok[slot0 + r0 + 128] * DIM + kk0;
    const ushort* B1e = W1 + (size_t)e * (DIM*DIM);
    const ushort* B2e = gated ? (WG + (size_t)e * (DIM*DIM))
                              : (W1 + (size_t)NE * (DIM*DIM));
    const ushort* pB1 = B1e + (size_t)(col0 + r0) * DIM + kk0;
    const ushort* pB2 = B2e + (size_t)(col0 + r0) * DIM + kk0;

    const int hi = lane >> 4, lr = lane & 15;
    int aoff[4], boff[4];
#pragma unroll
    for (int m = 0; m < 4; m++) {
        int row = wm*64 + m*16 + lr;
        int lrow = row >> 1;
        int sl = ((row & 1) << 2) | hi;
        aoff[m] = lrow*64 + (sl ^ (lrow & 7))*8;
    }
#pragma unroll
    for (int n = 0; n < 4; n++) {
        int oc = wn*64 + n*16 + lr;
        int lrow = oc >> 1;
        int sl = ((oc & 1) << 2) | hi;
        boff[n] = lrow*64 + (sl ^ (lrow & 7))*8;
    }

    f32x4 zero4 = {0.f, 0.f, 0.f, 0.f};
    f32x4 acc1[4][4], acc2[4][4];
#pragma unroll
    for (int m = 0; m < 4; m++)
#pragma unroll
        for (int n = 0; n < 4; n++) { acc1[m][n] = zero4; acc2[m][n] = zero4; }

    auto stage = [&](int buf, int kte) {
        ushort* b = &lds[buf * 16384];
        gll16(pA0 + kte, b + wofs);
        gll16(pA1 + kte, b + 4096 + wofs);
        gll16(pB1 + kte, b + 8192 + wofs);
        if (gated) gll16(pB2 + kte, b + 12288 + wofs);
    };
    auto compute = [&](int buf) {
        const ushort* Ab = &lds[buf * 16384];
        const ushort* Bb = Ab + 8192;
        bf16x8 a[4], bv[4];
#pragma unroll
        for (int m = 0; m < 4; m++) a[m] = *(const bf16x8*)(Ab + aoff[m]);
#pragma unroll
        for (int n = 0; n < 4; n++) bv[n] = *(const bf16x8*)(Bb + boff[n]);
        __builtin_amdgcn_s_setprio(1);
#pragma unroll
        for (int m = 0; m < 4; m++)
#pragma unroll
            for (int n = 0; n < 4; n++)
                acc1[m][n] = __builtin_amdgcn_mfma_f32_16x16x32_bf16(a[m], bv[n], acc1[m][n], 0, 0, 0);
        __builtin_amdgcn_s_setprio(0);
        if (gated) {
            const ushort* B2b = Ab + 12288;
            bf16x8 b2[4];
#pragma unroll
            for (int n = 0; n < 4; n++) b2[n] = *(const bf16x8*)(B2b + boff[n]);
            __builtin_amdgcn_s_setprio(1);
#pragma unroll
            for (int m = 0; m < 4; m++)
#pragma unroll
                for (int n = 0; n < 4; n++)
                    acc2[m][n] = __builtin_amdgcn_mfma_f32_16x16x32_bf16(a[m], b2[n], acc2[m][n], 0, 0, 0);
            __builtin_amdgcn_s_setprio(0);
        }
    };

    stage(0, 0);
    asm volatile("s_waitcnt vmcnt(0)" ::: "memory");
    __builtin_amdgcn_s_barrier();
    asm volatile("" ::: "memory");
    for (int t = 0; t < 31; ++t) {
        stage((t + 1) & 1, (t + 1) * 32);
        compute(t & 1);
        asm volatile("s_waitcnt vmcnt(0)" ::: "memory");
        __builtin_amdgcn_s_barrier();
        asm volatile("" ::: "memory");
    }
    compute(1);                                           // tile 31

#pragma unroll
    for (int m = 0; m < 4; m++)
#pragma unroll
        for (int n = 0; n < 4; n++)
#pragma unroll
            for (int r = 0; r < 4; r++) {
                int row = slot0 + wm*64 + m*16 + hi*4 + r;
                int col = col0 + wn*64 + n*16 + lr;
                float v1 = acc1[m][n][r];
                float h = gated ? siluf(v1) * acc2[m][n][r]
                                : siluf(v1 + sb1[col]);
                H[(size_t)row * DIM + col] = f2bf(h);
            }
}

// ---- G2: 256x128 single-B, 48 KB dbuf ---------------------------------------
__global__ void __launch_bounds__(512, 2)
g2_kernel(const ushort* __restrict__ H, const ushort* __restrict__ W2,
          const float* __restrict__ sb2, float* __restrict__ out,
          ushort* __restrict__ y2, const int* __restrict__ ctrl)
{
    __shared__ ushort lds[24576];   // 48 KB: 2 bufs x (8192 A + 4096 B)
    int bx, col0;
    {
        int L = blockIdx.x + blockIdx.y * MT_TILES;          // grid 136x8 = 1088
        int D = (L & 7) * MT_TILES + (L >> 3);
        bx = D >> 3;  col0 = (D & 7) * 128;
    }
    if (bx >= ctrl[0]) return;
    const int e     = ctrl[32 + 2*bx];
    const int slot0 = ctrl[32 + 2*bx + 1];
    const int sbase = ctrl[2];
    const int tt = threadIdx.x;
    const int lane = tt & 63, wid = tt >> 6;
    const int wm = wid >> 1, wn = wid & 1;
    const int wofs = wid * 512;

    const int slog = (tt & 7) ^ ((tt >> 3) & 7);
    const int kk0 = (slog & 3) * 8;
    const int r0 = ((tt >> 3) << 1) + (slog >> 2);
    const ushort* pA0 = H + (size_t)(slot0 + r0) * DIM + kk0;
    const ushort* pA1 = H + (size_t)(slot0 + r0 + 128) * DIM + kk0;
    const ushort* Be  = W2 + (size_t)e * (DIM*DIM);
    const ushort* pB1 = Be + (size_t)(col0 + r0) * DIM + kk0;

    const int hi = lane >> 4, lr = lane & 15;
    int aoff[4], boff[4];
#pragma unroll
    for (int m = 0; m < 4; m++) {
        int row = wm*64 + m*16 + lr;
        int lrow = row >> 1;
        int sl = ((row & 1) << 2) | hi;
        aoff[m] = lrow*64 + (sl ^ (lrow & 7))*8;
    }
#pragma unroll
    for (int n = 0; n < 4; n++) {
        int oc = wn*64 + n*16 + lr;
        int lrow = oc >> 1;
        int sl = ((oc & 1) << 2) | hi;
        boff[n] = lrow*64 + (sl ^ (lrow & 7))*8;
    }

    f32x4 zero4 = {0.f, 0.f, 0.f, 0.f};
    f32x4 acc[4][4];
#pragma unroll
    for (int m = 0; m < 4; m++)
#pragma unroll
        for (int n = 0; n < 4; n++) acc[m][n] = zero4;

    auto stage = [&](int buf, int kte) {
        ushort* b = &lds[buf * 12288];
        gll16(pA0 + kte, b + wofs);
        gll16(pA1 + kte, b + 4096 + wofs);
        gll16(pB1 + kte, b + 8192 + wofs);
    };
    auto compute = [&](int buf) {
        const ushort* Ab = &lds[buf * 12288];
        const ushort* Bb = Ab + 8192;
        bf16x8 a[4], bv[4];
#pragma unroll
        for (int m = 0; m < 4; m++) a[m] = *(const bf16x8*)(Ab + aoff[m]);
#pragma unroll
        for (int n = 0; n < 4; n++) bv[n] = *(const bf16x8*)(Bb + boff[n]);
        __builtin_amdgcn_s_setprio(1);
#pragma unroll
        for (int m = 0; m < 4; m++)
#pragma unroll
            for (int n = 0; n < 4; n++)
                acc[m][n] = __builtin_amdgcn_mfma_f32_16x16x32_bf16(a[m], bv[n], acc[m][n], 0, 0, 0);
        __builtin_amdgcn_s_setprio(0);
    };

    stage(0, 0);
    asm volatile("s_waitcnt vmcnt(0)" ::: "memory");
    __builtin_amdgcn_s_barrier();
    asm volatile("" ::: "memory");
    for (int t = 0; t < 31; ++t) {
        stage((t + 1) & 1, (t + 1) * 32);
        compute(t & 1);
        asm volatile("s_waitcnt vmcnt(0)" ::: "memory");
        __builtin_amdgcn_s_barrier();
        asm volatile("" ::: "memory");
    }
    compute(1);                                           // tile 31

#pragma unroll
    for (int m = 0; m < 4; m++)
#pragma unroll
        for (int n = 0; n < 4; n++)
#pragma unroll
            for (int r = 0; r < 4; r++) {
                int row = slot0 + wm*64 + m*16 + hi*4 + r;
                int col = col0 + wn*64 + n*16 + lr;
                float v = acc[m][n][r];
                if (e != NE) y2[(size_t)row * DIM + col] = f2bf(v);
                else         out[(size_t)(row - sbase) * DIM + col] = v + sb2[col];
            }
}

// --------- combine: out[n] += sum_k w_k * y2[slot_k(n)] ----------------------
__global__ void __launch_bounds__(256)
combine_kernel(const ushort* __restrict__ y2, const int* __restrict__ slots,
               const float* __restrict__ topk_w, float* __restrict__ out)
{
    __shared__ int ss[3];
    __shared__ float sw[3];
    const int n = blockIdx.x, tid = threadIdx.x;
    if (tid < 3) { ss[tid] = slots[n * 3 + tid]; sw[tid] = topk_w[n * 3 + tid]; }
    __syncthreads();
    float4* o4 = (float4*)(out + (size_t)n * DIM);
    float4 o = o4[tid];
#pragma unroll
    for (int k = 0; k < 3; k++) {
        const ushort4 yv = *(const ushort4*)(y2 + (size_t)ss[k] * DIM + tid * 4);
        float w = sw[k];
        o.x += w * bf2f(yv.x);
        o.y += w * bf2f(yv.y);
        o.z += w * bf2f(yv.z);
        o.w += w * bf2f(yv.w);
    }
    o4[tid] = o;
}

extern "C" void kernel_launch(void* const* d_in, const int* in_sizes, int n_in,
                              void* d_out, int out_size, void* d_ws, size_t ws_size,
                              hipStream_t stream)
{
    const float* x    = (const float*)d_in[0];
    const float* gw   = (const float*)d_in[1];
    const float* gb   = (const float*)d_in[2];
    const float* bia  = (const float*)d_in[3];
    const float* w1   = (const float*)d_in[4];
    const float* wg   = (const float*)d_in[5];
    const float* w2   = (const float*)d_in[6];
    const float* sw1  = (const float*)d_in[7];
    const float* sb1  = (const float*)d_in[8];
    const float* sw2  = (const float*)d_in[9];
    const float* sb2  = (const float*)d_in[10];
    float* out = (float*)d_out;

    // Workspace layout (bytes); total 173,452,288 <= proven ws_size >= 186,625,024.
    char* ws = (char*)d_ws;
    int*    ctrl   = (int*)   (ws + 0);          // [0]=ntiles [1]=rows [2]=shared_base, +8 counts, +16 cursors, +32 tiles
    int*    topk_e = (int*)   (ws + 4096);       //  98,304
    float*  topk_w = (float*) (ws + 102400);     //  98,304
    int*    slots  = (int*)   (ws + 200704);     //  98,304
    int*    row_tok= (int*)   (ws + 299008);     // 138,240 (34560 ints) -> pad to 437,248
    ushort* w1T    = (ushort*)(ws + 437248);     // 8 x 2MB (e7 = sw1T)
    ushort* wgT    = (ushort*)(ws + 17214464);   // 7 x 2MB
    ushort* w2T    = (ushort*)(ws + 31894528);   // 8 x 2MB (e7 = sw2T)
    ushort* h1     = (ushort*)(ws + 48671744);   // 34560 x 1024 bf16 = 70,778,880
    ushort* y2     = (ushort*)(ws + 119450624);  // 26368 x 1024 bf16 = 54,001,664 -> end 173,452,288
    ushort* xb     = y2;                         // alias: xb dead before g2 writes y2

    hipMemsetAsync(ctrl, 0, 4096, stream);
    hipMemsetAsync(row_tok, 0, 34560 * 4, stream);   // pad slots default to token 0
    prep_kernel<<<dim3(32, 32, 24), 256, 0, stream>>>(w1, wg, w2, sw1, sw2,
                                                      w1T, wgT, w2T,
                                                      x, gw, gb, bia,
                                                      topk_e, topk_w, ctrl + 8, xb);
    setup_kernel<<<1, 64, 0, stream>>>(ctrl);
    scatter_kernel<<<N_TOK / 256, 256, 0, stream>>>(topk_e, ctrl, row_tok, slots);

    g1_kernel<<<dim3(MT_TILES, 8), 512, 0, stream>>>(xb, w1T, wgT, sb1, h1,
                                                     row_tok, ctrl);
    g2_kernel<<<dim3(MT_TILES, 8), 512, 0, stream>>>(h1, w2T, sb2, out, y2, ctrl);
    combine_kernel<<<N_TOK, 256, 0, stream>>>(y2, slots, topk_w, out);
}

// Round 17
// 350.670 us; speedup vs baseline: 2.0534x; 1.0267x over previous
//
#include <hip/hip_runtime.h>
#include <hip/hip_bf16.h>

// DeepSeekMoE: B=4,S=2048,D=1024,H=1024,E=7,NS=1,topk=3. N=8192 tokens.
#define N_TOK 8192
#define DIM   1024
#define NE    7
#define MT_TILES 136   // <= 103 routed + 32 shared + slack; grids 136*8 = 1088

typedef __attribute__((ext_vector_type(8))) short bf16x8;
typedef __attribute__((ext_vector_type(4))) float f32x4;

typedef __attribute__((address_space(3))) ushort lds_us_t;
typedef __attribute__((address_space(1))) const ushort glb_us_t;

__device__ __forceinline__ void gll16(const ushort* g, ushort* l) {
    __builtin_amdgcn_global_load_lds((glb_us_t*)g, (lds_us_t*)l, 16, 0, 0);
}

__device__ __forceinline__ unsigned short f2bf(float f) {
    unsigned int u = __builtin_bit_cast(unsigned int, f);
    u += 0x7fffu + ((u >> 16) & 1u);   // RNE
    return (unsigned short)(u >> 16);
}

__device__ __forceinline__ float bf2f(unsigned short b) {
    unsigned int u = ((unsigned int)b) << 16;
    return __builtin_bit_cast(float, u);
}

__device__ __forceinline__ float siluf(float v) { return v / (1.f + __expf(-v)); }

// ---------------- prep: weight transpose+convert  ||  gate (fused) -----------
__global__ void __launch_bounds__(256)
prep_kernel(const float* __restrict__ w1, const float* __restrict__ wg,
            const float* __restrict__ w2, const float* __restrict__ sw1,
            const float* __restrict__ sw2,
            ushort* __restrict__ w1T, ushort* __restrict__ wgT,
            ushort* __restrict__ w2T,
            const float* __restrict__ x, const float* __restrict__ gw,
            const float* __restrict__ gb, const float* __restrict__ bia,
            int* __restrict__ topk_e, float* __restrict__ topk_w,
            int* __restrict__ counts, ushort* __restrict__ xb)
{
    __shared__ float smem[NE * DIM + 8];   // 28.7 KB, aliased by both branches
    const int tid = threadIdx.x;
    const int z = blockIdx.z;

    if (z < 23) {
        const float* src; ushort* dst;
        if (z < 7)       { src = w1 + (size_t)z * (DIM*DIM);        dst = w1T + (size_t)z * (DIM*DIM); }
        else if (z < 14) { src = wg + (size_t)(z - 7) * (DIM*DIM);  dst = wgT + (size_t)(z - 7) * (DIM*DIM); }
        else if (z < 21) { src = w2 + (size_t)(z - 14) * (DIM*DIM); dst = w2T + (size_t)(z - 14) * (DIM*DIM); }
        else if (z == 21){ src = sw1; dst = w1T + (size_t)NE * (DIM*DIM); }
        else             { src = sw2; dst = w2T + (size_t)NE * (DIM*DIM); }
        float (*t)[33] = (float(*)[33])smem;
        int bx = blockIdx.x * 32, by = blockIdx.y * 32;
        int lx = tid & 31, ly = tid >> 5;
#pragma unroll
        for (int i = 0; i < 32; i += 8)
            t[ly + i][lx] = src[(size_t)(by + ly + i) * DIM + bx + lx];
        __syncthreads();
#pragma unroll
        for (int i = 0; i < 32; i += 8) {
            int r = ly + i;
            dst[(size_t)(bx + r) * DIM + by + lx] = f2bf(t[lx][r]);
        }
        return;
    }

    float (*gwT)[DIM] = (float(*)[DIM])smem;
    int* cnt = (int*)(smem + NE * DIM);
    const int gblk = blockIdx.y * 32 + blockIdx.x;    // 0..1023
    if (tid < NE) cnt[tid] = 0;
    for (int t = tid; t < NE * DIM; t += 256) {
        int d = t / NE, e = t - d * NE;
        gwT[e][d] = gw[t];
    }
    __syncthreads();

    const int lane = tid & 63, wid = tid >> 6;
#pragma unroll
    for (int tt = 0; tt < 2; tt++) {
        const int n = gblk * 8 + wid * 2 + tt;
        const float4* xr = (const float4*)(x + (size_t)n * DIM);
        ushort4* xo = (ushort4*)(xb + (size_t)n * DIM);
        float p[NE];
#pragma unroll
        for (int e = 0; e < NE; e++) p[e] = 0.f;
#pragma unroll
        for (int it = 0; it < 4; it++) {
            int i4 = it * 64 + lane;
            float4 v = xr[i4];
            ushort4 o;
            o.x = f2bf(v.x); o.y = f2bf(v.y); o.z = f2bf(v.z); o.w = f2bf(v.w);
            xo[i4] = o;
            int d = i4 * 4;
#pragma unroll
            for (int e = 0; e < NE; e++) {
                float4 g = *(const float4*)&gwT[e][d];
                p[e] += v.x * g.x + v.y * g.y + v.z * g.z + v.w * g.w;
            }
        }
#pragma unroll
        for (int e = 0; e < NE; e++)
            for (int off = 32; off; off >>= 1) p[e] += __shfl_xor(p[e], off);
        if (lane == 0) {
            float l[NE], m = -1e30f;
#pragma unroll
            for (int e = 0; e < NE; e++) { l[e] = p[e] + gb[e]; m = fmaxf(m, l[e]); }
            float s = 0.f;
#pragma unroll
            for (int e = 0; e < NE; e++) { l[e] = __expf(l[e] - m); s += l[e]; }
            float inv = 1.f / s;
#pragma unroll
            for (int e = 0; e < NE; e++) l[e] *= inv;          // probs
            float adj[NE]; bool used[NE];
#pragma unroll
            for (int e = 0; e < NE; e++) { adj[e] = l[e] + bia[e]; used[e] = false; }
            int sel[3]; float w[3]; float ws = 0.f;
            for (int k = 0; k < 3; k++) {
                int b = -1; float bv = -1e30f;
                for (int e = 0; e < NE; e++)
                    if (!used[e] && adj[e] > bv) { bv = adj[e]; b = e; }
                used[b] = true; sel[k] = b; w[k] = l[b]; ws += w[k];
            }
            float iws = 1.f / ws;
            for (int k = 0; k < 3; k++) {
                topk_e[n * 3 + k] = sel[k];
                topk_w[n * 3 + k] = w[k] * iws;
                atomicAdd(&cnt[sel[k]], 1);
            }
        }
    }
    __syncthreads();
    if (tid < NE) atomicAdd(&counts[tid], cnt[tid]);
}

// --------- setup: thread-0 scan (7 experts) + parallel tile-list fill --------
__global__ void __launch_bounds__(64)
setup_kernel(int* __restrict__ ctrl)
{
    __shared__ int eoff[NE + 1];
    __shared__ int tb[NE + 1];
    const int tid = threadIdx.x;
    if (tid == 0) {
        int off = 0, t = 0;
        for (int e = 0; e < NE; e++) {
            eoff[e] = off;
            tb[e] = t;
            ctrl[16 + e] = off;                       // cursor
            int padc = (ctrl[8 + e] + 255) & ~255;
            off += padc;
            t += padc >> 8;
        }
        eoff[NE] = off;  tb[NE] = t;
        ctrl[2] = off;                                // shared_base
        ctrl[1] = off + N_TOK;                        // total rows
        ctrl[0] = t + (N_TOK >> 8);                   // tile count
    }
    __syncthreads();
    if (tid <= NE) {
        int* tiles = ctrl + 32;
        int o = eoff[tid];
        int t0 = tb[tid];
        int nt = (tid == NE) ? (N_TOK >> 8) : (tb[tid + 1] - tb[tid]);
        for (int i = 0; i < nt; i++) {
            tiles[(t0 + i) * 2]     = tid;            // expert id (NE = shared)
            tiles[(t0 + i) * 2 + 1] = o + i * 256;
        }
    }
}

// --------- scatter: block-aggregated slot reservation (+ ident fill) ---------
__global__ void __launch_bounds__(256)
scatter_kernel(const int* __restrict__ topk_e, int* __restrict__ ctrl,
               int* __restrict__ row_tok, int* __restrict__ slots)
{
    __shared__ int lcnt[NE];
    __shared__ int base[NE];
    const int tid = threadIdx.x;
    const int n = blockIdx.x * 256 + tid;
    if (tid < NE) lcnt[tid] = 0;
    __syncthreads();
    row_tok[ctrl[2] + n] = n;                         // identity fill (shared)
    int e[3], ofs[3];
#pragma unroll
    for (int k = 0; k < 3; k++) {
        e[k] = topk_e[n * 3 + k];
        ofs[k] = atomicAdd(&lcnt[e[k]], 1);           // LDS atomic
    }
    __syncthreads();
    if (tid < NE) base[tid] = atomicAdd(&ctrl[16 + tid], lcnt[tid]);
    __syncthreads();
#pragma unroll
    for (int k = 0; k < 3; k++) {
        int slot = base[e[k]] + ofs[k];
        row_tok[slot] = n;
        slots[n * 3 + k] = slot;
    }
}

// ============ GEMM: 2-barrier double-buffer (proven fastest schedule) ========
// Dual-row packed LDS swizzle (2 lanes/bank, free); gll16 linear dest with
// inverse-swizzled global source (rule #21).

// ---- G1: 256x128 dual-B, BK=64 dbuf (128 KB, 1 blk/CU) ----------------------
// 16 K-steps instead of 32 -> half the vmcnt(0) drains + barriers; port
// traffic, swizzle, fragment math unchanged. r7/r8 proved 1 blk/CU costs ~0.
// Per-buffer layout (ushorts): A-k0 [0,8192) A-k1 [8192,16384)
//   B1-k0 [16384,20480) B1-k1 [20480,24576) B2-k0 [24576,28672) B2-k1 [28672,32768)
__global__ void __launch_bounds__(512, 2)
g1_kernel(const ushort* __restrict__ Xb, const ushort* __restrict__ W1,
          const ushort* __restrict__ WG, const float* __restrict__ sb1,
          ushort* __restrict__ H, const int* __restrict__ row_tok,
          const int* __restrict__ ctrl)
{
    __shared__ ushort lds[65536];   // 128 KB: 2 bufs x 32768
    int bx, col0;
    {
        int L = blockIdx.x + blockIdx.y * MT_TILES;          // grid 136x8 = 1088
        int D = (L & 7) * MT_TILES + (L >> 3);
        bx = D >> 3;  col0 = (D & 7) * 128;
    }
    if (bx >= ctrl[0]) return;
    const int e     = ctrl[32 + 2*bx];
    const int slot0 = ctrl[32 + 2*bx + 1];
    const bool gated = (e != NE);
    const int tt = threadIdx.x;
    const int lane = tt & 63, wid = tt >> 6;
    const int wm = wid >> 1, wn = wid & 1;
    const int wofs = wid * 512;

    const int slog = (tt & 7) ^ ((tt >> 3) & 7);
    const int kk0 = (slog & 3) * 8;
    const int r0 = ((tt >> 3) << 1) + (slog >> 2);
    const ushort* pA0 = Xb + (size_t)row_tok[slot0 + r0] * DIM + kk0;
    const ushort* pA1 = Xb + (size_t)row_tok[slot0 + r0 + 128] * DIM + kk0;
    const ushort* B1e = W1 + (size_t)e * (DIM*DIM);
    const ushort* B2e = gated ? (WG + (size_t)e * (DIM*DIM))
                              : (W1 + (size_t)NE * (DIM*DIM));
    const ushort* pB1 = B1e + (size_t)(col0 + r0) * DIM + kk0;
    const ushort* pB2 = B2e + (size_t)(col0 + r0) * DIM + kk0;

    const int hi = lane >> 4, lr = lane & 15;
    int aoff[4], boff[4];
#pragma unroll
    for (int m = 0; m < 4; m++) {
        int row = wm*64 + m*16 + lr;
        int lrow = row >> 1;
        int sl = ((row & 1) << 2) | hi;
        aoff[m] = lrow*64 + (sl ^ (lrow & 7))*8;
    }
#pragma unroll
    for (int n = 0; n < 4; n++) {
        int oc = wn*64 + n*16 + lr;
        int lrow = oc >> 1;
        int sl = ((oc & 1) << 2) | hi;
        boff[n] = lrow*64 + (sl ^ (lrow & 7))*8;
    }

    f32x4 zero4 = {0.f, 0.f, 0.f, 0.f};
    f32x4 acc1[4][4], acc2[4][4];
#pragma unroll
    for (int m = 0; m < 4; m++)
#pragma unroll
        for (int n = 0; n < 4; n++) { acc1[m][n] = zero4; acc2[m][n] = zero4; }

    auto stage = [&](int buf, int kte) {   // kte = K-tile base (ushorts), 64-wide
        ushort* b = &lds[buf * 32768];
        gll16(pA0 + kte,      b + wofs);
        gll16(pA0 + kte + 32, b + 8192 + wofs);
        gll16(pA1 + kte,      b + 4096 + wofs);
        gll16(pA1 + kte + 32, b + 12288 + wofs);
        gll16(pB1 + kte,      b + 16384 + wofs);
        gll16(pB1 + kte + 32, b + 20480 + wofs);
        if (gated) {
            gll16(pB2 + kte,      b + 24576 + wofs);
            gll16(pB2 + kte + 32, b + 28672 + wofs);
        }
    };
    auto compute = [&](int buf, int half) {
        const ushort* Ab = &lds[buf * 32768 + half * 8192];
        const ushort* Bb = &lds[buf * 32768 + 16384 + half * 4096];
        bf16x8 a[4], bv[4];
#pragma unroll
        for (int m = 0; m < 4; m++) a[m] = *(const bf16x8*)(Ab + aoff[m]);
#pragma unroll
        for (int n = 0; n < 4; n++) bv[n] = *(const bf16x8*)(Bb + boff[n]);
        __builtin_amdgcn_s_setprio(1);
#pragma unroll
        for (int m = 0; m < 4; m++)
#pragma unroll
            for (int n = 0; n < 4; n++)
                acc1[m][n] = __builtin_amdgcn_mfma_f32_16x16x32_bf16(a[m], bv[n], acc1[m][n], 0, 0, 0);
        __builtin_amdgcn_s_setprio(0);
        if (gated) {
            const ushort* B2b = &lds[buf * 32768 + 24576 + half * 4096];
            bf16x8 b2[4];
#pragma unroll
            for (int n = 0; n < 4; n++) b2[n] = *(const bf16x8*)(B2b + boff[n]);
            __builtin_amdgcn_s_setprio(1);
#pragma unroll
            for (int m = 0; m < 4; m++)
#pragma unroll
                for (int n = 0; n < 4; n++)
                    acc2[m][n] = __builtin_amdgcn_mfma_f32_16x16x32_bf16(a[m], b2[n], acc2[m][n], 0, 0, 0);
            __builtin_amdgcn_s_setprio(0);
        }
    };

    stage(0, 0);
    asm volatile("s_waitcnt vmcnt(0)" ::: "memory");
    __builtin_amdgcn_s_barrier();
    asm volatile("" ::: "memory");
    for (int t = 0; t < 15; ++t) {          // 16 K-tiles of 64
        stage((t + 1) & 1, (t + 1) * 64);
        compute(t & 1, 0);
        compute(t & 1, 1);
        asm volatile("s_waitcnt vmcnt(0)" ::: "memory");
        __builtin_amdgcn_s_barrier();
        asm volatile("" ::: "memory");
    }
    compute(1, 0);                          // K-tile 15
    compute(1, 1);

    // epilogue: SwiGLU (routed) / bias-silu (shared)
#pragma unroll
    for (int m = 0; m < 4; m++)
#pragma unroll
        for (int n = 0; n < 4; n++)
#pragma unroll
            for (int r = 0; r < 4; r++) {
                int row = slot0 + wm*64 + m*16 + hi*4 + r;
                int col = col0 + wn*64 + n*16 + lr;
                float v1 = acc1[m][n][r];
                float h = gated ? siluf(v1) * acc2[m][n][r]
                                : siluf(v1 + sb1[col]);
                H[(size_t)row * DIM + col] = f2bf(h);
            }
}

// ---- G2: 256x128 single-B, 48 KB dbuf (unchanged r14) -----------------------
__global__ void __launch_bounds__(512, 2)
g2_kernel(const ushort* __restrict__ H, const ushort* __restrict__ W2,
          const float* __restrict__ sb2, float* __restrict__ out,
          ushort* __restrict__ y2, const int* __restrict__ ctrl)
{
    __shared__ ushort lds[24576];   // 48 KB: 2 bufs x (8192 A + 4096 B)
    int bx, col0;
    {
        int L = blockIdx.x + blockIdx.y * MT_TILES;          // grid 136x8 = 1088
        int D = (L & 7) * MT_TILES + (L >> 3);
        bx = D >> 3;  col0 = (D & 7) * 128;
    }
    if (bx >= ctrl[0]) return;
    const int e     = ctrl[32 + 2*bx];
    const int slot0 = ctrl[32 + 2*bx + 1];
    const int sbase = ctrl[2];
    const int tt = threadIdx.x;
    const int lane = tt & 63, wid = tt >> 6;
    const int wm = wid >> 1, wn = wid & 1;
    const int wofs = wid * 512;

    const int slog = (tt & 7) ^ ((tt >> 3) & 7);
    const int kk0 = (slog & 3) * 8;
    const int r0 = ((tt >> 3) << 1) + (slog >> 2);
    const ushort* pA0 = H + (size_t)(slot0 + r0) * DIM + kk0;
    const ushort* pA1 = H + (size_t)(slot0 + r0 + 128) * DIM + kk0;
    const ushort* Be  = W2 + (size_t)e * (DIM*DIM);
    const ushort* pB1 = Be + (size_t)(col0 + r0) * DIM + kk0;

    const int hi = lane >> 4, lr = lane & 15;
    int aoff[4], boff[4];
#pragma unroll
    for (int m = 0; m < 4; m++) {
        int row = wm*64 + m*16 + lr;
        int lrow = row >> 1;
        int sl = ((row & 1) << 2) | hi;
        aoff[m] = lrow*64 + (sl ^ (lrow & 7))*8;
    }
#pragma unroll
    for (int n = 0; n < 4; n++) {
        int oc = wn*64 + n*16 + lr;
        int lrow = oc >> 1;
        int sl = ((oc & 1) << 2) | hi;
        boff[n] = lrow*64 + (sl ^ (lrow & 7))*8;
    }

    f32x4 zero4 = {0.f, 0.f, 0.f, 0.f};
    f32x4 acc[4][4];
#pragma unroll
    for (int m = 0; m < 4; m++)
#pragma unroll
        for (int n = 0; n < 4; n++) acc[m][n] = zero4;

    auto stage = [&](int buf, int kte) {
        ushort* b = &lds[buf * 12288];
        gll16(pA0 + kte, b + wofs);
        gll16(pA1 + kte, b + 4096 + wofs);
        gll16(pB1 + kte, b + 8192 + wofs);
    };
    auto compute = [&](int buf) {
        const ushort* Ab = &lds[buf * 12288];
        const ushort* Bb = Ab + 8192;
        bf16x8 a[4], bv[4];
#pragma unroll
        for (int m = 0; m < 4; m++) a[m] = *(const bf16x8*)(Ab + aoff[m]);
#pragma unroll
        for (int n = 0; n < 4; n++) bv[n] = *(const bf16x8*)(Bb + boff[n]);
        __builtin_amdgcn_s_setprio(1);
#pragma unroll
        for (int m = 0; m < 4; m++)
#pragma unroll
            for (int n = 0; n < 4; n++)
                acc[m][n] = __builtin_amdgcn_mfma_f32_16x16x32_bf16(a[m], bv[n], acc[m][n], 0, 0, 0);
        __builtin_amdgcn_s_setprio(0);
    };

    stage(0, 0);
    asm volatile("s_waitcnt vmcnt(0)" ::: "memory");
    __builtin_amdgcn_s_barrier();
    asm volatile("" ::: "memory");
    for (int t = 0; t < 31; ++t) {
        stage((t + 1) & 1, (t + 1) * 32);
        compute(t & 1);
        asm volatile("s_waitcnt vmcnt(0)" ::: "memory");
        __builtin_amdgcn_s_barrier();
        asm volatile("" ::: "memory");
    }
    compute(1);                                           // tile 31

#pragma unroll
    for (int m = 0; m < 4; m++)
#pragma unroll
        for (int n = 0; n < 4; n++)
#pragma unroll
            for (int r = 0; r < 4; r++) {
                int row = slot0 + wm*64 + m*16 + hi*4 + r;
                int col = col0 + wn*64 + n*16 + lr;
                float v = acc[m][n][r];
                if (e != NE) y2[(size_t)row * DIM + col] = f2bf(v);
                else         out[(size_t)(row - sbase) * DIM + col] = v + sb2[col];
            }
}

// --------- combine: out[n] += sum_k w_k * y2[slot_k(n)] ----------------------
__global__ void __launch_bounds__(256)
combine_kernel(const ushort* __restrict__ y2, const int* __restrict__ slots,
               const float* __restrict__ topk_w, float* __restrict__ out)
{
    __shared__ int ss[3];
    __shared__ float sw[3];
    const int n = blockIdx.x, tid = threadIdx.x;
    if (tid < 3) { ss[tid] = slots[n * 3 + tid]; sw[tid] = topk_w[n * 3 + tid]; }
    __syncthreads();
    float4* o4 = (float4*)(out + (size_t)n * DIM);
    float4 o = o4[tid];
#pragma unroll
    for (int k = 0; k < 3; k++) {
        const ushort4 yv = *(const ushort4*)(y2 + (size_t)ss[k] * DIM + tid * 4);
        float w = sw[k];
        o.x += w * bf2f(yv.x);
        o.y += w * bf2f(yv.y);
        o.z += w * bf2f(yv.z);
        o.w += w * bf2f(yv.w);
    }
    o4[tid] = o;
}

extern "C" void kernel_launch(void* const* d_in, const int* in_sizes, int n_in,
                              void* d_out, int out_size, void* d_ws, size_t ws_size,
                              hipStream_t stream)
{
    const float* x    = (const float*)d_in[0];
    const float* gw   = (const float*)d_in[1];
    const float* gb   = (const float*)d_in[2];
    const float* bia  = (const float*)d_in[3];
    const float* w1   = (const float*)d_in[4];
    const float* wg   = (const float*)d_in[5];
    const float* w2   = (const float*)d_in[6];
    const float* sw1  = (const float*)d_in[7];
    const float* sb1  = (const float*)d_in[8];
    const float* sw2  = (const float*)d_in[9];
    const float* sb2  = (const float*)d_in[10];
    float* out = (float*)d_out;

    // Workspace layout (bytes); total 173,452,288 <= proven ws_size >= 186,625,024.
    char* ws = (char*)d_ws;
    int*    ctrl   = (int*)   (ws + 0);          // [0]=ntiles [1]=rows [2]=shared_base, +8 counts, +16 cursors, +32 tiles
    int*    topk_e = (int*)   (ws + 4096);       //  98,304
    float*  topk_w = (float*) (ws + 102400);     //  98,304
    int*    slots  = (int*)   (ws + 200704);     //  98,304
    int*    row_tok= (int*)   (ws + 299008);     // 138,240 (34560 ints) -> pad to 437,248
    ushort* w1T    = (ushort*)(ws + 437248);     // 8 x 2MB (e7 = sw1T)
    ushort* wgT    = (ushort*)(ws + 17214464);   // 7 x 2MB
    ushort* w2T    = (ushort*)(ws + 31894528);   // 8 x 2MB (e7 = sw2T)
    ushort* h1     = (ushort*)(ws + 48671744);   // 34560 x 1024 bf16 = 70,778,880
    ushort* y2     = (ushort*)(ws + 119450624);  // 26368 x 1024 bf16 = 54,001,664 -> end 173,452,288
    ushort* xb     = y2;                         // alias: xb dead before g2 writes y2

    hipMemsetAsync(ctrl, 0, 4096, stream);
    hipMemsetAsync(row_tok, 0, 34560 * 4, stream);   // pad slots default to token 0
    prep_kernel<<<dim3(32, 32, 24), 256, 0, stream>>>(w1, wg, w2, sw1, sw2,
                                                      w1T, wgT, w2T,
                                                      x, gw, gb, bia,
                                                      topk_e, topk_w, ctrl + 8, xb);
    setup_kernel<<<1, 64, 0, stream>>>(ctrl);
    scatter_kernel<<<N_TOK / 256, 256, 0, stream>>>(topk_e, ctrl, row_tok, slots);

    g1_kernel<<<dim3(MT_TILES, 8), 512, 0, stream>>>(xb, w1T, wgT, sb1, h1,
                                                     row_tok, ctrl);
    g2_kernel<<<dim3(MT_TILES, 8), 512, 0, stream>>>(h1, w2T, sb2, out, y2, ctrl);
    combine_kernel<<<N_TOK, 256, 0, stream>>>(y2, slots, topk_w, out);
}